// Round 1
// baseline (298.085 us; speedup 1.0000x reference)
//
#include <hip/hip_runtime.h>
#include <hip/hip_fp16.h>

namespace {

constexpr int S = 512;   // plane height/width
constexpr int C = 64;    // channels per plane

struct alignas(8) H4 { __half2 a, b; };

// ---------------------------------------------------------------------------
// Transpose (3, C, S, S) f32  ->  (3, S, S, C) f16
// Block = 256 threads, handles one (p, y, 64-wide x tile).
// Reads: each block touches exactly 64 channels x 64 x x 4B = 16KB, and every
// 128B line it pulls is fully consumed within the block (L1-resident tile).
// Writes: 16 lanes x 8B = 128B contiguous per texel, wave writes 512B runs.
// ---------------------------------------------------------------------------
__global__ __launch_bounds__(256) void tp_transpose(const float* __restrict__ tp,
                                                    __half* __restrict__ dst)
{
    int b  = blockIdx.x;
    int xt = b & 7;              // 8 x-tiles of 64
    int y  = (b >> 3) & (S - 1);
    int p  = b >> 12;            // 0..2
    int t  = threadIdx.x;
    int cq = t & 15;             // channel-quad id: channels 4cq..4cq+3
    int xl = t >> 4;             // 0..15
    int x0 = xt * 64;

    const float* src = tp + (size_t)p * C * (S * S) + (size_t)y * S + x0;
    __half*      ob  = dst + ((size_t)(p * S + y) * S + x0) * C;

    #pragma unroll
    for (int xk = 0; xk < 4; ++xk) {
        int x = xl + xk * 16;
        float f0 = src[(size_t)(4 * cq + 0) * (S * S) + x];
        float f1 = src[(size_t)(4 * cq + 1) * (S * S) + x];
        float f2 = src[(size_t)(4 * cq + 2) * (S * S) + x];
        float f3 = src[(size_t)(4 * cq + 3) * (S * S) + x];
        H4 h;
        h.a = __floats2half2_rn(f0, f1);
        h.b = __floats2half2_rn(f2, f3);
        *reinterpret_cast<H4*>(ob + (size_t)x * C + 4 * cq) = h;
    }
}

// ---------------------------------------------------------------------------
// Main sampler: one 16-lane group per (sample, plane); lane t covers channels
// 4t..4t+3.  Gathers 4 corners (8B half4 each, 128B contiguous per group),
// bilinear blend in f32, coalesced float4 store.
// Output layout: out[s*192 + p*64 + c] = out[grp*64 + c] with grp = s*3+p.
// ---------------------------------------------------------------------------
__global__ __launch_bounds__(256) void tp_sample(const float* __restrict__ coords,
                                                 const __half* __restrict__ planes,
                                                 float* __restrict__ out,
                                                 int total_sp)
{
    int tid = blockIdx.x * 256 + threadIdx.x;
    int grp = tid >> 4;              // sample-plane id = s*3 + p
    if (grp >= total_sp) return;
    int t = tid & 15;

    int s = grp / 3;
    int p = grp - s * 3;

    float cx = coords[3 * s + 0];
    float cy = coords[3 * s + 1];
    float cz = coords[3 * s + 2];
    // plane 0: (x,y)  plane 1: (x,z)  plane 2: (z,y)
    float gx = (p == 2) ? cz : cx;
    float gy = (p == 1) ? cz : cy;

    float ix = (gx + 1.0f) * 256.0f - 0.5f;   // ((gx+1)*512 - 1) * 0.5, exact
    float iy = (gy + 1.0f) * 256.0f - 0.5f;
    float x0f = floorf(ix), y0f = floorf(iy);
    float wx = ix - x0f, wy = iy - y0f;
    int x0 = (int)x0f, y0 = (int)y0f;
    int x1 = x0 + 1,   y1 = y0 + 1;

    bool vx0 = ((unsigned)x0 < (unsigned)S);
    bool vx1 = ((unsigned)x1 < (unsigned)S);
    bool vy0 = ((unsigned)y0 < (unsigned)S);
    bool vy1 = ((unsigned)y1 < (unsigned)S);

    float w00 = (vx0 && vy0) ? (1.0f - wy) * (1.0f - wx) : 0.0f;
    float w01 = (vx1 && vy0) ? (1.0f - wy) * wx          : 0.0f;
    float w10 = (vx0 && vy1) ? wy * (1.0f - wx)          : 0.0f;
    float w11 = (vx1 && vy1) ? wy * wx                   : 0.0f;

    int xc0 = min(max(x0, 0), S - 1), xc1 = min(max(x1, 0), S - 1);
    int yc0 = min(max(y0, 0), S - 1), yc1 = min(max(y1, 0), S - 1);

    const __half* pb = planes + (size_t)p * (S * S * C) + 4 * t;
    H4 v00 = *reinterpret_cast<const H4*>(pb + (size_t)(yc0 * S + xc0) * C);
    H4 v01 = *reinterpret_cast<const H4*>(pb + (size_t)(yc0 * S + xc1) * C);
    H4 v10 = *reinterpret_cast<const H4*>(pb + (size_t)(yc1 * S + xc0) * C);
    H4 v11 = *reinterpret_cast<const H4*>(pb + (size_t)(yc1 * S + xc1) * C);

    float2 a00 = __half22float2(v00.a), b00 = __half22float2(v00.b);
    float2 a01 = __half22float2(v01.a), b01 = __half22float2(v01.b);
    float2 a10 = __half22float2(v10.a), b10 = __half22float2(v10.b);
    float2 a11 = __half22float2(v11.a), b11 = __half22float2(v11.b);

    float4 r;
    r.x = w00 * a00.x + w01 * a01.x + w10 * a10.x + w11 * a11.x;
    r.y = w00 * a00.y + w01 * a01.y + w10 * a10.y + w11 * a11.y;
    r.z = w00 * b00.x + w01 * b01.x + w10 * b10.x + w11 * b11.x;
    r.w = w00 * b00.y + w01 * b01.y + w10 * b10.y + w11 * b11.y;

    *reinterpret_cast<float4*>(out + (size_t)grp * 64 + 4 * t) = r;
}

// ---------------------------------------------------------------------------
// Fallback: gather straight from channel-major f32 tplanes (slow but correct)
// in case ws_size cannot hold the transposed fp16 planes.
// ---------------------------------------------------------------------------
__global__ __launch_bounds__(256) void tp_sample_direct(const float* __restrict__ coords,
                                                        const float* __restrict__ tp,
                                                        float* __restrict__ out,
                                                        int total_sp)
{
    int tid = blockIdx.x * 256 + threadIdx.x;
    int grp = tid >> 4;
    if (grp >= total_sp) return;
    int t = tid & 15;

    int s = grp / 3;
    int p = grp - s * 3;

    float cx = coords[3 * s + 0];
    float cy = coords[3 * s + 1];
    float cz = coords[3 * s + 2];
    float gx = (p == 2) ? cz : cx;
    float gy = (p == 1) ? cz : cy;

    float ix = (gx + 1.0f) * 256.0f - 0.5f;
    float iy = (gy + 1.0f) * 256.0f - 0.5f;
    float x0f = floorf(ix), y0f = floorf(iy);
    float wx = ix - x0f, wy = iy - y0f;
    int x0 = (int)x0f, y0 = (int)y0f;
    int x1 = x0 + 1,   y1 = y0 + 1;

    bool vx0 = ((unsigned)x0 < (unsigned)S);
    bool vx1 = ((unsigned)x1 < (unsigned)S);
    bool vy0 = ((unsigned)y0 < (unsigned)S);
    bool vy1 = ((unsigned)y1 < (unsigned)S);

    float w00 = (vx0 && vy0) ? (1.0f - wy) * (1.0f - wx) : 0.0f;
    float w01 = (vx1 && vy0) ? (1.0f - wy) * wx          : 0.0f;
    float w10 = (vx0 && vy1) ? wy * (1.0f - wx)          : 0.0f;
    float w11 = (vx1 && vy1) ? wy * wx                   : 0.0f;

    int xc0 = min(max(x0, 0), S - 1), xc1 = min(max(x1, 0), S - 1);
    int yc0 = min(max(y0, 0), S - 1), yc1 = min(max(y1, 0), S - 1);

    int o00 = yc0 * S + xc0, o01 = yc0 * S + xc1;
    int o10 = yc1 * S + xc0, o11 = yc1 * S + xc1;

    const float* pb = tp + (size_t)p * C * (S * S);
    float r[4];
    #pragma unroll
    for (int j = 0; j < 4; ++j) {
        const float* ch = pb + (size_t)(4 * t + j) * (S * S);
        r[j] = w00 * ch[o00] + w01 * ch[o01] + w10 * ch[o10] + w11 * ch[o11];
    }
    float4 v = make_float4(r[0], r[1], r[2], r[3]);
    *reinterpret_cast<float4*>(out + (size_t)grp * 64 + 4 * t) = v;
}

} // namespace

extern "C" void kernel_launch(void* const* d_in, const int* in_sizes, int n_in,
                              void* d_out, int out_size, void* d_ws, size_t ws_size,
                              hipStream_t stream)
{
    const float* coords  = (const float*)d_in[0];  // (N, M, 3) f32
    const float* tplanes = (const float*)d_in[1];  // (1, 3, C, S, S) f32
    float* out = (float*)d_out;                    // (N, M, 3*C) f32

    // total sample-planes = N*M*3 == element count of coords
    int total_sp = in_sizes[0];
    int sample_blocks = (total_sp * 16 + 255) / 256;

    size_t need = (size_t)3 * S * S * C * sizeof(__half);  // 100.7 MB
    if (ws_size >= need) {
        __half* ws = (__half*)d_ws;
        tp_transpose<<<3 * S * 8, 256, 0, stream>>>(tplanes, ws);
        tp_sample<<<sample_blocks, 256, 0, stream>>>(coords, ws, out, total_sp);
    } else {
        tp_sample_direct<<<sample_blocks, 256, 0, stream>>>(coords, tplanes, out, total_sp);
    }
}

// Round 2
// 231.336 us; speedup vs baseline: 1.2885x; 1.2885x over previous
//
#include <hip/hip_runtime.h>
#include <hip/hip_fp16.h>

namespace {

constexpr int S = 512;   // plane height/width
constexpr int C = 64;    // channels per plane

typedef float f32x4 __attribute__((ext_vector_type(4)));
struct alignas(8) H4 { __half2 a, b; };

// ---------------------------------------------------------------------------
// Transpose (3, C, S, S) f32  ->  (3, S, S, C) f16
// Block = 256 threads, one (p, y, 64-wide x tile).
// Each lane reads float4 along x for 4 channels (16 x 64B segments per
// wave-load, full HBM granule), writes H4 (128B contiguous per 16 lanes).
// ---------------------------------------------------------------------------
__global__ __launch_bounds__(256) void tp_transpose(const float* __restrict__ tp,
                                                    __half* __restrict__ dst)
{
    int b  = blockIdx.x;
    int xt = b & 7;              // 8 x-tiles of 64
    int y  = (b >> 3) & (S - 1);
    int p  = b >> 12;            // 0..2
    int t  = threadIdx.x;
    int cq = t & 15;             // channel-quad id: channels 4cq..4cq+3
    int xl = t >> 4;             // 0..15: x-quad, covers x = 4*xl..4*xl+3
    int xb = xt * 64;

    const float* src = tp + (size_t)p * C * (S * S) + (size_t)y * S + xb + xl * 4;

    float4 f[4];
    #pragma unroll
    for (int j = 0; j < 4; ++j)
        f[j] = *reinterpret_cast<const float4*>(src + (size_t)(4 * cq + j) * (S * S));

    __half* ob = dst + ((size_t)(p * S + y) * S + xb) * C + 4 * cq;

    #pragma unroll
    for (int kx = 0; kx < 4; ++kx) {
        H4 h;
        h.a = __floats2half2_rn(((const float*)&f[0])[kx], ((const float*)&f[1])[kx]);
        h.b = __floats2half2_rn(((const float*)&f[2])[kx], ((const float*)&f[3])[kx]);
        *reinterpret_cast<H4*>(ob + (size_t)(xl * 4 + kx) * C) = h;
    }
}

// ---------------------------------------------------------------------------
// Main sampler: 8 lanes per (sample, plane); lane t covers channels
// {4t..4t+3} and {32+4t..32+4t+3}.  Per corner: 2 x H4 loads (8 lanes x 8B =
// 64B contiguous per instruction).  Bilinear blend in f32, two 128B-coalesced
// nontemporal float4 stores (output is streaming, keep L2 for plane gathers).
// ---------------------------------------------------------------------------
__global__ __launch_bounds__(256) void tp_sample(const float* __restrict__ coords,
                                                 const __half* __restrict__ planes,
                                                 float* __restrict__ out,
                                                 int total_sp)
{
    int tid = blockIdx.x * 256 + threadIdx.x;
    int grp = tid >> 3;              // sample-plane id = s*3 + p
    if (grp >= total_sp) return;
    int t = tid & 7;

    int s = grp / 3;
    int p = grp - s * 3;

    float cx = coords[3 * s + 0];
    float cy = coords[3 * s + 1];
    float cz = coords[3 * s + 2];
    // plane 0: (x,y)  plane 1: (x,z)  plane 2: (z,y)
    float gx = (p == 2) ? cz : cx;
    float gy = (p == 1) ? cz : cy;

    float ix = (gx + 1.0f) * 256.0f - 0.5f;   // ((gx+1)*512 - 1) * 0.5, exact
    float iy = (gy + 1.0f) * 256.0f - 0.5f;
    float x0f = floorf(ix), y0f = floorf(iy);
    float wx = ix - x0f, wy = iy - y0f;
    int x0 = (int)x0f, y0 = (int)y0f;
    int x1 = x0 + 1,   y1 = y0 + 1;

    bool vx0 = ((unsigned)x0 < (unsigned)S);
    bool vx1 = ((unsigned)x1 < (unsigned)S);
    bool vy0 = ((unsigned)y0 < (unsigned)S);
    bool vy1 = ((unsigned)y1 < (unsigned)S);

    float w00 = (vx0 && vy0) ? (1.0f - wy) * (1.0f - wx) : 0.0f;
    float w01 = (vx1 && vy0) ? (1.0f - wy) * wx          : 0.0f;
    float w10 = (vx0 && vy1) ? wy * (1.0f - wx)          : 0.0f;
    float w11 = (vx1 && vy1) ? wy * wx                   : 0.0f;

    int xc0 = min(max(x0, 0), S - 1), xc1 = min(max(x1, 0), S - 1);
    int yc0 = min(max(y0, 0), S - 1), yc1 = min(max(y1, 0), S - 1);

    const __half* pb = planes + (size_t)p * (S * S * C);
    size_t o00 = (size_t)(yc0 * S + xc0) * C, o01 = (size_t)(yc0 * S + xc1) * C;
    size_t o10 = (size_t)(yc1 * S + xc0) * C, o11 = (size_t)(yc1 * S + xc1) * C;

    #pragma unroll
    for (int h = 0; h < 2; ++h) {
        int c = 4 * t + 32 * h;
        H4 v00 = *reinterpret_cast<const H4*>(pb + o00 + c);
        H4 v01 = *reinterpret_cast<const H4*>(pb + o01 + c);
        H4 v10 = *reinterpret_cast<const H4*>(pb + o10 + c);
        H4 v11 = *reinterpret_cast<const H4*>(pb + o11 + c);

        float2 a00 = __half22float2(v00.a), b00 = __half22float2(v00.b);
        float2 a01 = __half22float2(v01.a), b01 = __half22float2(v01.b);
        float2 a10 = __half22float2(v10.a), b10 = __half22float2(v10.b);
        float2 a11 = __half22float2(v11.a), b11 = __half22float2(v11.b);

        f32x4 r;
        r.x = w00 * a00.x + w01 * a01.x + w10 * a10.x + w11 * a11.x;
        r.y = w00 * a00.y + w01 * a01.y + w10 * a10.y + w11 * a11.y;
        r.z = w00 * b00.x + w01 * b01.x + w10 * b10.x + w11 * b11.x;
        r.w = w00 * b00.y + w01 * b01.y + w10 * b10.y + w11 * b11.y;

        __builtin_nontemporal_store(r, reinterpret_cast<f32x4*>(out + (size_t)grp * 64 + c));
    }
}

// ---------------------------------------------------------------------------
// Fallback: gather straight from channel-major f32 tplanes (slow but correct)
// in case ws_size cannot hold the transposed fp16 planes.
// ---------------------------------------------------------------------------
__global__ __launch_bounds__(256) void tp_sample_direct(const float* __restrict__ coords,
                                                        const float* __restrict__ tp,
                                                        float* __restrict__ out,
                                                        int total_sp)
{
    int tid = blockIdx.x * 256 + threadIdx.x;
    int grp = tid >> 4;
    if (grp >= total_sp) return;
    int t = tid & 15;

    int s = grp / 3;
    int p = grp - s * 3;

    float cx = coords[3 * s + 0];
    float cy = coords[3 * s + 1];
    float cz = coords[3 * s + 2];
    float gx = (p == 2) ? cz : cx;
    float gy = (p == 1) ? cz : cy;

    float ix = (gx + 1.0f) * 256.0f - 0.5f;
    float iy = (gy + 1.0f) * 256.0f - 0.5f;
    float x0f = floorf(ix), y0f = floorf(iy);
    float wx = ix - x0f, wy = iy - y0f;
    int x0 = (int)x0f, y0 = (int)y0f;
    int x1 = x0 + 1,   y1 = y0 + 1;

    bool vx0 = ((unsigned)x0 < (unsigned)S);
    bool vx1 = ((unsigned)x1 < (unsigned)S);
    bool vy0 = ((unsigned)y0 < (unsigned)S);
    bool vy1 = ((unsigned)y1 < (unsigned)S);

    float w00 = (vx0 && vy0) ? (1.0f - wy) * (1.0f - wx) : 0.0f;
    float w01 = (vx1 && vy0) ? (1.0f - wy) * wx          : 0.0f;
    float w10 = (vx0 && vy1) ? wy * (1.0f - wx)          : 0.0f;
    float w11 = (vx1 && vy1) ? wy * wx                   : 0.0f;

    int xc0 = min(max(x0, 0), S - 1), xc1 = min(max(x1, 0), S - 1);
    int yc0 = min(max(y0, 0), S - 1), yc1 = min(max(y1, 0), S - 1);

    int o00 = yc0 * S + xc0, o01 = yc0 * S + xc1;
    int o10 = yc1 * S + xc0, o11 = yc1 * S + xc1;

    const float* pb = tp + (size_t)p * C * (S * S);
    float r[4];
    #pragma unroll
    for (int j = 0; j < 4; ++j) {
        const float* ch = pb + (size_t)(4 * t + j) * (S * S);
        r[j] = w00 * ch[o00] + w01 * ch[o01] + w10 * ch[o10] + w11 * ch[o11];
    }
    float4 v = make_float4(r[0], r[1], r[2], r[3]);
    *reinterpret_cast<float4*>(out + (size_t)grp * 64 + 4 * t) = v;
}

} // namespace

extern "C" void kernel_launch(void* const* d_in, const int* in_sizes, int n_in,
                              void* d_out, int out_size, void* d_ws, size_t ws_size,
                              hipStream_t stream)
{
    const float* coords  = (const float*)d_in[0];  // (N, M, 3) f32
    const float* tplanes = (const float*)d_in[1];  // (1, 3, C, S, S) f32
    float* out = (float*)d_out;                    // (N, M, 3*C) f32

    int total_sp = in_sizes[0];                    // N*M*3

    size_t need = (size_t)3 * S * S * C * sizeof(__half);  // 100.7 MB
    if (ws_size >= need) {
        __half* ws = (__half*)d_ws;
        tp_transpose<<<3 * S * 8, 256, 0, stream>>>(tplanes, ws);
        int sample_blocks = (total_sp * 8 + 255) / 256;
        tp_sample<<<sample_blocks, 256, 0, stream>>>(coords, ws, out, total_sp);
    } else {
        int sample_blocks = (total_sp * 16 + 255) / 256;
        tp_sample_direct<<<sample_blocks, 256, 0, stream>>>(coords, tplanes, out, total_sp);
    }
}